// Round 13
// baseline (197.014 us; speedup 1.0000x reference)
//
#include <hip/hip_runtime.h>

#define NPIX    65536
#define D       64
#define KCODES  1024
#define PIXB    64
#define BLOCK   512
#define XPAD    68                 // xs (fp32) row stride in floats
#define CAP     64                 // per-pixel candidate list capacity
#define GFAC    0.036f             // certified gate factor (2B=0.0316 + slack)

// d_out layout (floats):
//   [0]                  loss
//   [1 .. 4194305)       quantized_out (NCHW, 16x64x64x64)
//   [4194305]            perplexity
//   [4194306 .. 71303170) encodings (65536 x 1024)
//   [71303170 .. 71368706) indices (as float)
#define QUANT_OFF 1
#define PERP_OFF  4194305
#define ENC_OFF   4194306u
#define IDX_OFF   71303170u

// d_ws layout:
//   [0..8)        double loss_sum
//   [8..4104)     int counts[1024]
//   [4104..8200)  float se[1024]
//   [8320..139392) unsigned short ebf[1024*64]  (bf16 codebook, 16B-aligned)

typedef float f32x4 __attribute__((ext_vector_type(4)));
typedef short bf16x8 __attribute__((ext_vector_type(8)));

// RNE float->bf16 bits (deterministic, matches hardware RNE)
__device__ __forceinline__ unsigned short f2bf(float f) {
    unsigned u = __float_as_uint(f);
    return (unsigned short)((u + 0x7fffu + ((u >> 16) & 1u)) >> 16);
}

// numpy pairwise_sum (n=64): 8 accumulators stride-8, then
// ((r0+r1)+(r2+r3))+((r4+r5)+(r6+r7)); __f*_rn blocks contraction.
__global__ __launch_bounds__(256) void vq_init(const float* __restrict__ emb,
                                               double* __restrict__ loss_sum,
                                               int* __restrict__ counts,
                                               float* __restrict__ se,
                                               unsigned short* __restrict__ ebf) {
    int t = blockIdx.x * 256 + threadIdx.x;
    if (t == 0) *loss_sum = 0.0;
    if (t < KCODES) {
        counts[t] = 0;
        const float* e = emb + (size_t)t * D;
        float r[8];
        #pragma unroll
        for (int j = 0; j < 8; ++j) r[j] = __fmul_rn(e[j], e[j]);
        #pragma unroll
        for (int i = 8; i < D; i += 8)
            #pragma unroll
            for (int j = 0; j < 8; ++j)
                r[j] = __fadd_rn(r[j], __fmul_rn(e[i + j], e[i + j]));
        float X = __fadd_rn(__fadd_rn(r[0], r[1]), __fadd_rn(r[2], r[3]));
        float Y = __fadd_rn(__fadd_rn(r[4], r[5]), __fadd_rn(r[6], r[7]));
        se[t] = __fadd_rn(X, Y);
        // bf16 codebook row (RNE) for the MFMA screen
        #pragma unroll
        for (int j = 0; j < D; ++j) ebf[(t << 6) + j] = f2bf(e[j]);
    }
}

// MFMA bf16 screen (certified gate) + exact numpy-chain recheck.
// R13: encodings write moved to dedicated vq_enc (fill-rate writer); xb LDS
// dropped (A-fragments packed from xs per-ks in registers); LDS ~33 KB.
__global__ __launch_bounds__(512) void vq_main(const float* __restrict__ in,
                                               const float* __restrict__ emb,
                                               const float* __restrict__ se,
                                               const unsigned short* __restrict__ ebf,
                                               float* __restrict__ out,
                                               double* __restrict__ loss_sum,
                                               int* __restrict__ counts) {
    __shared__ float xs[PIXB][XPAD];          // 17408 B (fp32, exact math)
    __shared__ float sls[KCODES];             // 4096 B
    __shared__ float wmin[8][PIXB];
    __shared__ float gate[PIXB];
    __shared__ float sxs[PIXB];
    __shared__ float smx[PIXB];
    __shared__ float semaxsq;
    __shared__ int   cnt[PIXB];
    __shared__ unsigned short list[PIXB][CAP];
    __shared__ int   skfin[PIXB];

    const int tid  = threadIdx.x;
    const int lane = tid & 63;
    const int wid  = tid >> 6;                // 0..7
    const int n0   = blockIdx.x * PIXB;
    const int b    = n0 >> 12;
    const int s0   = n0 & 4095;

    // stage x tile (transpose) fp32, and se into LDS
    {
        const float* base = in + ((size_t)b << 18) + s0;
        #pragma unroll
        for (int i = 0; i < 8; ++i) {
            int d = wid + (i << 3);
            xs[lane][d] = base[((size_t)d << 12) + lane];
        }
        sls[tid] = se[tid];
        sls[tid + 512] = se[tid + 512];
    }
    __syncthreads();

    // tid<64: exact numpy pairwise sx per pixel + partial max of se
    if (tid < PIXB) {
        float r[8];
        #pragma unroll
        for (int j = 0; j < 8; ++j) {
            float v = xs[tid][j];
            r[j] = __fmul_rn(v, v);
        }
        #pragma unroll
        for (int i = 8; i < D; i += 8)
            #pragma unroll
            for (int j = 0; j < 8; ++j) {
                float v = xs[tid][i + j];
                r[j] = __fadd_rn(r[j], __fmul_rn(v, v));
            }
        float X = __fadd_rn(__fadd_rn(r[0], r[1]), __fadd_rn(r[2], r[3]));
        float Y = __fadd_rn(__fadd_rn(r[4], r[5]), __fadd_rn(r[6], r[7]));
        sxs[tid] = __fadd_rn(X, Y);
        float mx = sls[tid << 4];
        #pragma unroll
        for (int j = 1; j < 16; ++j) mx = fmaxf(mx, sls[(tid << 4) + j]);
        smx[tid] = mx;
    }

    const int wbase = wid * 128;
    const int arow  = lane & 15;              // A row / B col within tile
    const int kgrp  = (lane >> 4) << 3;       // k-offset of this lane's 8 elems
    const int rbase = (lane >> 4) << 2;       // D row base

    // ---------------- P1: screen, per-wave per-pixel min ----------------
    float mreg[4][4];
    #pragma unroll
    for (int pt = 0; pt < 4; ++pt)
        #pragma unroll
        for (int r = 0; r < 4; ++r) mreg[pt][r] = 3.0e38f;

    #pragma unroll
    for (int s = 0; s < 2; ++s) {
        const int cbase = wbase + s * 64;
        f32x4 acc[4][4];
        #pragma unroll
        for (int pt = 0; pt < 4; ++pt)
            #pragma unroll
            for (int kt = 0; kt < 4; ++kt) acc[pt][kt] = (f32x4){0.f, 0.f, 0.f, 0.f};
        #pragma unroll
        for (int ks = 0; ks < 2; ++ks) {
            // pack A-fragments for this ks from xs (short live range)
            bf16x8 afk[4];
            #pragma unroll
            for (int pt = 0; pt < 4; ++pt) {
                const float* xp = &xs[pt * 16 + arow][ks * 32 + kgrp];
                bf16x8 v;
                #pragma unroll
                for (int j = 0; j < 8; ++j) v[j] = (short)f2bf(xp[j]);
                afk[pt] = v;
            }
            #pragma unroll
            for (int kt = 0; kt < 4; ++kt) {
                int code = cbase + kt * 16 + arow;
                bf16x8 bf_ = *(const bf16x8*)(ebf + ((size_t)code << 6) + ks * 32 + kgrp);
                #pragma unroll
                for (int pt = 0; pt < 4; ++pt)
                    acc[pt][kt] = __builtin_amdgcn_mfma_f32_16x16x32_bf16(
                        afk[pt], bf_, acc[pt][kt], 0, 0, 0);
            }
        }
        #pragma unroll
        for (int pt = 0; pt < 4; ++pt)
            #pragma unroll
            for (int kt = 0; kt < 4; ++kt) {
                int code = cbase + kt * 16 + arow;
                #pragma unroll
                for (int r = 0; r < 4; ++r) {
                    float sv = __fsub_rn(sls[code], __fmul_rn(2.0f, acc[pt][kt][r]));
                    mreg[pt][r] = fminf(mreg[pt][r], sv);
                }
            }
    }
    #pragma unroll
    for (int m = 1; m < 16; m <<= 1)
        #pragma unroll
        for (int pt = 0; pt < 4; ++pt)
            #pragma unroll
            for (int r = 0; r < 4; ++r)
                mreg[pt][r] = fminf(mreg[pt][r], __shfl_xor(mreg[pt][r], m));
    if (arow == 0) {
        #pragma unroll
        for (int pt = 0; pt < 4; ++pt)
            #pragma unroll
            for (int r = 0; r < 4; ++r)
                wmin[wid][pt * 16 + rbase + r] = mreg[pt][r];
    }
    __syncthreads();

    if (tid == 0) {
        float mx = smx[0];
        #pragma unroll
        for (int j = 1; j < PIXB; ++j) mx = fmaxf(mx, smx[j]);
        semaxsq = mx;
    }
    __syncthreads();

    if (tid < PIXB) {
        float gm = wmin[0][tid];
        #pragma unroll
        for (int w = 1; w < 8; ++w) gm = fminf(gm, wmin[w][tid]);
        gate[tid] = gm + GFAC * sqrtf(sxs[tid] * semaxsq);
        cnt[tid] = 0;
    }
    __syncthreads();

    // ---------------- P2: recompute screen, append gated candidates -----
    #pragma unroll
    for (int s = 0; s < 2; ++s) {
        const int cbase = wbase + s * 64;
        f32x4 acc[4][4];
        #pragma unroll
        for (int pt = 0; pt < 4; ++pt)
            #pragma unroll
            for (int kt = 0; kt < 4; ++kt) acc[pt][kt] = (f32x4){0.f, 0.f, 0.f, 0.f};
        #pragma unroll
        for (int ks = 0; ks < 2; ++ks) {
            bf16x8 afk[4];
            #pragma unroll
            for (int pt = 0; pt < 4; ++pt) {
                const float* xp = &xs[pt * 16 + arow][ks * 32 + kgrp];
                bf16x8 v;
                #pragma unroll
                for (int j = 0; j < 8; ++j) v[j] = (short)f2bf(xp[j]);
                afk[pt] = v;
            }
            #pragma unroll
            for (int kt = 0; kt < 4; ++kt) {
                int code = cbase + kt * 16 + arow;
                bf16x8 bf_ = *(const bf16x8*)(ebf + ((size_t)code << 6) + ks * 32 + kgrp);
                #pragma unroll
                for (int pt = 0; pt < 4; ++pt)
                    acc[pt][kt] = __builtin_amdgcn_mfma_f32_16x16x32_bf16(
                        afk[pt], bf_, acc[pt][kt], 0, 0, 0);
            }
        }
        #pragma unroll
        for (int pt = 0; pt < 4; ++pt)
            #pragma unroll
            for (int kt = 0; kt < 4; ++kt) {
                int code = cbase + kt * 16 + arow;
                #pragma unroll
                for (int r = 0; r < 4; ++r) {
                    float sv = __fsub_rn(sls[code], __fmul_rn(2.0f, acc[pt][kt][r]));
                    int px = pt * 16 + rbase + r;
                    if (sv <= gate[px]) {
                        int slot = atomicAdd(&cnt[px], 1);
                        if (slot < CAP) list[px][slot] = (unsigned short)code;
                    }
                }
            }
    }
    __syncthreads();

    // ---------------- P3: exact numpy-chain recheck over gated set ------
    {
        const int px = tid >> 3, c0 = tid & 7;
        const int cn = cnt[px];
        float bv = 3.0e38f;
        int   bk = 0x7fffffff;
        if (cn > CAP) {
            // overflow fallback: exact full scan (correctness-preserving)
            for (int k = c0; k < KCODES; k += 8) {
                const float* er = emb + ((size_t)k << 6);
                float m = 0.f;
                #pragma unroll
                for (int d = 0; d < D; ++d) m = fmaf(xs[px][d], er[d], m);
                float sv = __fsub_rn(__fadd_rn(sxs[px], sls[k]), __fmul_rn(2.0f, m));
                if (sv < bv || (sv == bv && k < bk)) { bv = sv; bk = k; }
            }
        } else {
            for (int i = c0; i < cn; i += 8) {
                int k = list[px][i];
                const float* er = emb + ((size_t)k << 6);
                float m = 0.f;
                #pragma unroll
                for (int d = 0; d < D; ++d) m = fmaf(xs[px][d], er[d], m);
                float sv = __fsub_rn(__fadd_rn(sxs[px], sls[k]), __fmul_rn(2.0f, m));
                if (sv < bv || (sv == bv && k < bk)) { bv = sv; bk = k; }
            }
        }
        #pragma unroll
        for (int m = 4; m; m >>= 1) {
            float ov = __shfl_xor(bv, m);
            int   ok = __shfl_xor(bk, m);
            if (ov < bv || (ov == bv && ok < bk)) { bv = ov; bk = ok; }
        }
        if (c0 == 0) {
            skfin[px] = bk;
            atomicAdd(&counts[bk], 1);
            out[IDX_OFF + (unsigned)(n0 + px)] = (float)bk;
        }
    }
    __syncthreads();

    // ------- epilogue: quantized (NCHW) + mse, all 8 waves cooperate ----
    {
        float* qbase = out + QUANT_OFF + ((size_t)b << 18) + s0;
        float mse = 0.f;
        #pragma unroll
        for (int i = 0; i < 8; ++i) {
            int d = (wid << 3) + i;
            float q = emb[((size_t)skfin[lane] << 6) + d];
            qbase[((size_t)d << 12) + lane] = q;
            float df = q - xs[lane][d];
            mse = fmaf(df, df, mse);
        }
        #pragma unroll
        for (int off = 32; off; off >>= 1) mse += __shfl_down(mse, off);
        if (lane == 0) atomicAdd(loss_sum, (double)mse);
    }
}

// Dedicated one-hot writer: streams 256 KB/block at fill-rate. Reads the
// indices vq_main just wrote into d_out (stream-ordered dependency).
__global__ __launch_bounds__(512) void vq_enc(float* __restrict__ out) {
    __shared__ int kf[PIXB];
    const int tid = threadIdx.x;
    const int n0  = blockIdx.x * PIXB;
    if (tid < PIXB) kf[tid] = (int)out[IDX_OFF + (unsigned)(n0 + tid)];
    __syncthreads();

    // region [n0*1024+2, n0*1024+65534) as aligned float4; head/tail float2
    float4* dst4 = (float4*)(out + ENC_OFF + (size_t)n0 * KCODES + 2);
    for (int i = tid; i < 16383; i += BLOCK) {
        int flat = (i << 2) + 2;
        int r0 = flat >> 10;
        int r1 = (flat + 3) >> 10;
        int k0 = kf[r0];
        int k1 = kf[r1];
        int c  = flat & 1023;
        float4 v;
        v.x = (c == k0) ? 1.f : 0.f;
        v.y = (c + 1 == k0) ? 1.f : 0.f;
        v.z = (((flat + 2) & 1023) == k1) ? 1.f : 0.f;
        v.w = (((flat + 3) & 1023) == k1) ? 1.f : 0.f;
        dst4[i] = v;
    }
    if (tid == 0) {
        float2* dh = (float2*)(out + ENC_OFF + (size_t)n0 * KCODES);
        int kh = kf[0];
        float2 h2; h2.x = (kh == 0) ? 1.f : 0.f; h2.y = (kh == 1) ? 1.f : 0.f;
        *dh = h2;
        float2* dt = (float2*)(out + ENC_OFF + (size_t)n0 * KCODES + 65534);
        int kt = kf[63];
        float2 t2; t2.x = (kt == 1022) ? 1.f : 0.f; t2.y = (kt == 1023) ? 1.f : 0.f;
        *dt = t2;
    }
}

__global__ __launch_bounds__(256) void vq_fin(const double* __restrict__ loss_sum,
                                              const int* __restrict__ counts,
                                              float* __restrict__ out) {
    __shared__ double red[256];
    int t = threadIdx.x;
    double ent = 0.0;
    for (int k = t; k < KCODES; k += 256) {
        double p = (double)counts[k] / 65536.0;
        ent -= p * log(p + 1e-10);
    }
    red[t] = ent;
    __syncthreads();
    for (int o = 128; o; o >>= 1) {
        if (t < o) red[t] += red[t + o];
        __syncthreads();
    }
    if (t == 0) {
        out[PERP_OFF] = (float)exp(red[0]);
        out[0] = (float)(1.25 * (*loss_sum) / 4194304.0);
    }
}

extern "C" void kernel_launch(void* const* d_in, const int* in_sizes, int n_in,
                              void* d_out, int out_size, void* d_ws, size_t ws_size,
                              hipStream_t stream) {
    const float* in  = (const float*)d_in[0];
    const float* emb = (const float*)d_in[1];
    float* out = (float*)d_out;

    double*         loss_sum = (double*)d_ws;
    int*            counts   = (int*)((char*)d_ws + 8);
    float*          se       = (float*)((char*)d_ws + 4104);
    unsigned short* ebf      = (unsigned short*)((char*)d_ws + 8320);

    vq_init<<<4, 256, 0, stream>>>(emb, loss_sum, counts, se, ebf);
    vq_main<<<NPIX / PIXB, BLOCK, 0, stream>>>(in, emb, se, ebf, out, loss_sum, counts);
    vq_enc<<<NPIX / PIXB, BLOCK, 0, stream>>>(out);
    vq_fin<<<1, 256, 0, stream>>>(loss_sum, counts, out);
}

// Round 14
// 164.318 us; speedup vs baseline: 1.1990x; 1.1990x over previous
//
#include <hip/hip_runtime.h>

#define NPIX    65536
#define D       64
#define KCODES  1024
#define PIXB    64
#define BLOCK   512
#define XPAD    68                 // xs (fp32) row stride in floats
#define CAP     64                 // per-pixel candidate list capacity
#define GFAC    0.036f             // certified gate factor (2B=0.0316 + slack)

// d_out layout (floats):
//   [0] loss | [1..4194305) quantized | [4194305] perplexity
//   [4194306..71303170) encodings | [71303170..) indices
#define QUANT_OFF 1
#define PERP_OFF  4194305
#define ENC_OFF   4194306u
#define IDX_OFF   71303170u

// d_ws layout:
//   [0..8) double loss_sum | [8..4104) int counts[1024]
//   [4104..8200) float se[1024] | [8200..8204) int semax_bits
//   [8320..139392) unsigned short ebf[1024*64]

typedef float f32x4 __attribute__((ext_vector_type(4)));
typedef short bf16x8 __attribute__((ext_vector_type(8)));

// RNE float->bf16 bits (deterministic, matches hardware RNE)
__device__ __forceinline__ unsigned short f2bf(float f) {
    unsigned u = __float_as_uint(f);
    return (unsigned short)((u + 0x7fffu + ((u >> 16) & 1u)) >> 16);
}

// numpy pairwise_sum (n=64): 8 accumulators stride-8, then
// ((r0+r1)+(r2+r3))+((r4+r5)+(r6+r7)); __f*_rn blocks contraction.
__global__ __launch_bounds__(256) void vq_init(const float* __restrict__ emb,
                                               double* __restrict__ loss_sum,
                                               int* __restrict__ counts,
                                               float* __restrict__ se,
                                               int* __restrict__ semax_bits,
                                               unsigned short* __restrict__ ebf) {
    int t = blockIdx.x * 256 + threadIdx.x;
    if (t == 0) *loss_sum = 0.0;
    if (t < KCODES) {
        counts[t] = 0;
        const float* e = emb + (size_t)t * D;
        float r[8];
        #pragma unroll
        for (int j = 0; j < 8; ++j) r[j] = __fmul_rn(e[j], e[j]);
        #pragma unroll
        for (int i = 8; i < D; i += 8)
            #pragma unroll
            for (int j = 0; j < 8; ++j)
                r[j] = __fadd_rn(r[j], __fmul_rn(e[i + j], e[i + j]));
        float X = __fadd_rn(__fadd_rn(r[0], r[1]), __fadd_rn(r[2], r[3]));
        float Y = __fadd_rn(__fadd_rn(r[4], r[5]), __fadd_rn(r[6], r[7]));
        float S = __fadd_rn(X, Y);
        se[t] = S;
        // positive floats compare correctly as signed ints; poison 0xAA.. is
        // negative; stale-huge values only widen the gate (still correct).
        atomicMax(semax_bits, __float_as_int(S));
        #pragma unroll
        for (int j = 0; j < D; ++j) ebf[(t << 6) + j] = f2bf(e[j]);
    }
}

// Fused: MFMA bf16 screen (certified gate) + exact numpy-chain recheck +
// quantized/loss + one-hot stream. R14: ebf from ws, A-frags in 16 VGPR,
// acc[4][2] subpasses (peak VGPR down), semax precomputed, zero-fill enc.
__global__ __launch_bounds__(512) void vq_main(const float* __restrict__ in,
                                               const float* __restrict__ emb,
                                               const float* __restrict__ se,
                                               const int* __restrict__ semax_bits,
                                               const unsigned short* __restrict__ ebf,
                                               float* __restrict__ out,
                                               double* __restrict__ loss_sum,
                                               int* __restrict__ counts) {
    __shared__ float xs[PIXB][XPAD];          // 17408 B (fp32, exact math)
    __shared__ float sls[KCODES];             // 4096 B
    __shared__ float wmin[8][PIXB];           // 2048 B
    __shared__ float gate[PIXB];
    __shared__ float sxs[PIXB];
    __shared__ int   cnt[PIXB];
    __shared__ int   skfin[PIXB];
    __shared__ unsigned short list[PIXB][CAP];// 8192 B

    const int tid  = threadIdx.x;
    const int lane = tid & 63;
    const int wid  = tid >> 6;                // 0..7
    const int n0   = blockIdx.x * PIXB;
    const int b    = n0 >> 12;
    const int s0   = n0 & 4095;

    // stage x tile (transpose) fp32, and se into LDS
    {
        const float* base = in + ((size_t)b << 18) + s0;
        #pragma unroll
        for (int i = 0; i < 8; ++i) {
            int d = wid + (i << 3);
            xs[lane][d] = base[((size_t)d << 12) + lane];
        }
        sls[tid] = se[tid];
        sls[tid + 512] = se[tid + 512];
    }
    __syncthreads();                          // B1

    // wave 0: exact numpy pairwise sx per pixel (needed only at gate, B2)
    if (tid < PIXB) {
        cnt[tid] = 0;
        float r[8];
        #pragma unroll
        for (int j = 0; j < 8; ++j) {
            float v = xs[tid][j];
            r[j] = __fmul_rn(v, v);
        }
        #pragma unroll
        for (int i = 8; i < D; i += 8)
            #pragma unroll
            for (int j = 0; j < 8; ++j) {
                float v = xs[tid][i + j];
                r[j] = __fadd_rn(r[j], __fmul_rn(v, v));
            }
        float X = __fadd_rn(__fadd_rn(r[0], r[1]), __fadd_rn(r[2], r[3]));
        float Y = __fadd_rn(__fadd_rn(r[4], r[5]), __fadd_rn(r[6], r[7]));
        sxs[tid] = __fadd_rn(X, Y);
    }

    const int wbase = wid * 128;
    const int arow  = lane & 15;              // A row / B col within tile
    const int kgrp  = (lane >> 4) << 3;       // k-offset of this lane's 8 elems
    const int rbase = (lane >> 4) << 2;       // D row base

    // A-fragments: packed once, live for both passes (16 VGPR)
    bf16x8 af[2][4];
    #pragma unroll
    for (int ks = 0; ks < 2; ++ks)
        #pragma unroll
        for (int pt = 0; pt < 4; ++pt) {
            const float* xp = &xs[pt * 16 + arow][ks * 32 + kgrp];
            bf16x8 v;
            #pragma unroll
            for (int j = 0; j < 8; ++j) v[j] = (short)f2bf(xp[j]);
            af[ks][pt] = v;
        }

    // ---------------- P1: screen, per-wave per-pixel min ----------------
    float mreg[4][4];
    #pragma unroll
    for (int pt = 0; pt < 4; ++pt)
        #pragma unroll
        for (int r = 0; r < 4; ++r) mreg[pt][r] = 3.0e38f;

    #pragma unroll
    for (int s2 = 0; s2 < 4; ++s2) {
        const int cbase = wbase + s2 * 32;
        f32x4 acc[4][2];
        #pragma unroll
        for (int pt = 0; pt < 4; ++pt)
            #pragma unroll
            for (int kt = 0; kt < 2; ++kt) acc[pt][kt] = (f32x4){0.f, 0.f, 0.f, 0.f};
        #pragma unroll
        for (int ks = 0; ks < 2; ++ks)
            #pragma unroll
            for (int kt = 0; kt < 2; ++kt) {
                int code = cbase + kt * 16 + arow;
                bf16x8 bf_ = *(const bf16x8*)(ebf + ((size_t)code << 6) + ks * 32 + kgrp);
                #pragma unroll
                for (int pt = 0; pt < 4; ++pt)
                    acc[pt][kt] = __builtin_amdgcn_mfma_f32_16x16x32_bf16(
                        af[ks][pt], bf_, acc[pt][kt], 0, 0, 0);
            }
        #pragma unroll
        for (int pt = 0; pt < 4; ++pt)
            #pragma unroll
            for (int kt = 0; kt < 2; ++kt) {
                int code = cbase + kt * 16 + arow;
                #pragma unroll
                for (int r = 0; r < 4; ++r) {
                    float sv = __fsub_rn(sls[code], __fmul_rn(2.0f, acc[pt][kt][r]));
                    mreg[pt][r] = fminf(mreg[pt][r], sv);
                }
            }
    }
    #pragma unroll
    for (int m = 1; m < 16; m <<= 1)
        #pragma unroll
        for (int pt = 0; pt < 4; ++pt)
            #pragma unroll
            for (int r = 0; r < 4; ++r)
                mreg[pt][r] = fminf(mreg[pt][r], __shfl_xor(mreg[pt][r], m));
    if (arow == 0) {
        #pragma unroll
        for (int pt = 0; pt < 4; ++pt)
            #pragma unroll
            for (int r = 0; r < 4; ++r)
                wmin[wid][pt * 16 + rbase + r] = mreg[pt][r];
    }
    __syncthreads();                          // B2

    if (tid < PIXB) {
        float gm = wmin[0][tid];
        #pragma unroll
        for (int w = 1; w < 8; ++w) gm = fminf(gm, wmin[w][tid]);
        float semax = __int_as_float(*semax_bits);
        gate[tid] = gm + GFAC * sqrtf(sxs[tid] * semax);
    }
    __syncthreads();                          // B3

    // ---------------- P2: recompute screen, append gated candidates -----
    #pragma unroll
    for (int s2 = 0; s2 < 4; ++s2) {
        const int cbase = wbase + s2 * 32;
        f32x4 acc[4][2];
        #pragma unroll
        for (int pt = 0; pt < 4; ++pt)
            #pragma unroll
            for (int kt = 0; kt < 2; ++kt) acc[pt][kt] = (f32x4){0.f, 0.f, 0.f, 0.f};
        #pragma unroll
        for (int ks = 0; ks < 2; ++ks)
            #pragma unroll
            for (int kt = 0; kt < 2; ++kt) {
                int code = cbase + kt * 16 + arow;
                bf16x8 bf_ = *(const bf16x8*)(ebf + ((size_t)code << 6) + ks * 32 + kgrp);
                #pragma unroll
                for (int pt = 0; pt < 4; ++pt)
                    acc[pt][kt] = __builtin_amdgcn_mfma_f32_16x16x32_bf16(
                        af[ks][pt], bf_, acc[pt][kt], 0, 0, 0);
            }
        #pragma unroll
        for (int pt = 0; pt < 4; ++pt)
            #pragma unroll
            for (int kt = 0; kt < 2; ++kt) {
                int code = cbase + kt * 16 + arow;
                #pragma unroll
                for (int r = 0; r < 4; ++r) {
                    float sv = __fsub_rn(sls[code], __fmul_rn(2.0f, acc[pt][kt][r]));
                    int px = pt * 16 + rbase + r;
                    if (sv <= gate[px]) {
                        int slot = atomicAdd(&cnt[px], 1);
                        if (slot < CAP) list[px][slot] = (unsigned short)code;
                    }
                }
            }
    }
    __syncthreads();                          // B4

    // ---------------- P3: exact numpy-chain recheck over gated set ------
    {
        const int px = tid >> 3, c0 = tid & 7;
        const int cn = cnt[px];
        float bv = 3.0e38f;
        int   bk = 0x7fffffff;
        if (cn > CAP || cn == 0) {
            // overflow / degenerate-gate fallback: exact full scan
            for (int k = c0; k < KCODES; k += 8) {
                const float* er = emb + ((size_t)k << 6);
                float m = 0.f;
                #pragma unroll
                for (int d = 0; d < D; ++d) m = fmaf(xs[px][d], er[d], m);
                float sv = __fsub_rn(__fadd_rn(sxs[px], sls[k]), __fmul_rn(2.0f, m));
                if (sv < bv || (sv == bv && k < bk)) { bv = sv; bk = k; }
            }
        } else {
            for (int i = c0; i < cn; i += 8) {
                int k = list[px][i];
                const float* er = emb + ((size_t)k << 6);
                float m = 0.f;
                #pragma unroll
                for (int d = 0; d < D; ++d) m = fmaf(xs[px][d], er[d], m);
                float sv = __fsub_rn(__fadd_rn(sxs[px], sls[k]), __fmul_rn(2.0f, m));
                if (sv < bv || (sv == bv && k < bk)) { bv = sv; bk = k; }
            }
        }
        #pragma unroll
        for (int m = 4; m; m >>= 1) {
            float ov = __shfl_xor(bv, m);
            int   ok = __shfl_xor(bk, m);
            if (ov < bv || (ov == bv && ok < bk)) { bv = ov; bk = ok; }
        }
        if (c0 == 0) {
            skfin[px] = bk;
            atomicAdd(&counts[bk], 1);
            out[IDX_OFF + (unsigned)(n0 + px)] = (float)bk;
        }
    }
    __syncthreads();                          // B5

    // ------- epilogue: quantized (NCHW) + mse, all 8 waves cooperate ----
    {
        float* qbase = out + QUANT_OFF + ((size_t)b << 18) + s0;
        float mse = 0.f;
        #pragma unroll
        for (int i = 0; i < 8; ++i) {
            int d = (wid << 3) + i;
            float q = emb[((size_t)skfin[lane] << 6) + d];
            qbase[((size_t)d << 12) + lane] = q;
            float df = q - xs[lane][d];
            mse = fmaf(df, df, mse);
        }
        #pragma unroll
        for (int off = 32; off; off >>= 1) mse += __shfl_down(mse, off);
        if (lane == 0) atomicAdd(loss_sum, (double)mse);
    }

    // one-hot encodings: constant zero-fill (float4 body + float2 head/tail),
    // then 64 scalar 1.0 writes. No per-iter LDS reads/compares.
    {
        float4* dst4 = (float4*)(out + ENC_OFF + (size_t)n0 * KCODES + 2);
        const float4 z = {0.f, 0.f, 0.f, 0.f};
        for (int i = tid; i < 16383; i += BLOCK) dst4[i] = z;
        if (tid == 0) {
            const float2 z2 = {0.f, 0.f};
            *(float2*)(out + ENC_OFF + (size_t)n0 * KCODES) = z2;
            *(float2*)(out + ENC_OFF + (size_t)n0 * KCODES + 65534) = z2;
        }
    }
    __syncthreads();                          // B6: zeros before ones
    if (tid < PIXB)
        out[ENC_OFF + (size_t)(n0 + tid) * KCODES + (unsigned)skfin[tid]] = 1.0f;
}

__global__ __launch_bounds__(256) void vq_fin(const double* __restrict__ loss_sum,
                                              const int* __restrict__ counts,
                                              float* __restrict__ out) {
    __shared__ double red[256];
    int t = threadIdx.x;
    double ent = 0.0;
    for (int k = t; k < KCODES; k += 256) {
        double p = (double)counts[k] / 65536.0;
        ent -= p * log(p + 1e-10);
    }
    red[t] = ent;
    __syncthreads();
    for (int o = 128; o; o >>= 1) {
        if (t < o) red[t] += red[t + o];
        __syncthreads();
    }
    if (t == 0) {
        out[PERP_OFF] = (float)exp(red[0]);
        out[0] = (float)(1.25 * (*loss_sum) / 4194304.0);
    }
}

extern "C" void kernel_launch(void* const* d_in, const int* in_sizes, int n_in,
                              void* d_out, int out_size, void* d_ws, size_t ws_size,
                              hipStream_t stream) {
    const float* in  = (const float*)d_in[0];
    const float* emb = (const float*)d_in[1];
    float* out = (float*)d_out;

    double*         loss_sum   = (double*)d_ws;
    int*            counts     = (int*)((char*)d_ws + 8);
    float*          se         = (float*)((char*)d_ws + 4104);
    int*            semax_bits = (int*)((char*)d_ws + 8200);
    unsigned short* ebf        = (unsigned short*)((char*)d_ws + 8320);

    vq_init<<<4, 256, 0, stream>>>(emb, loss_sum, counts, se, semax_bits, ebf);
    vq_main<<<NPIX / PIXB, BLOCK, 0, stream>>>(in, emb, se, semax_bits, ebf,
                                               out, loss_sum, counts);
    vq_fin<<<1, 256, 0, stream>>>(loss_sum, counts, out);
}